// Round 3
// baseline (342.404 us; speedup 1.0000x reference)
//
#include <hip/hip_runtime.h>

#define T_TOK 2048
#define DIM   512
#define MOE   256
#define NE    64
#define NG    8
#define TOPKG 4
#define TOPK  8
#define CAP   1024
#define MOE_SCALE 2.5f

typedef float f32x4 __attribute__((ext_vector_type(4)));
typedef short s16x8 __attribute__((ext_vector_type(8)));

__device__ __forceinline__ unsigned short f2bf(float f) {
    unsigned u = __builtin_bit_cast(unsigned, f);
    unsigned r = (u + 0x7fffu + ((u >> 16) & 1u)) >> 16;
    return (unsigned short)r;
}

// ---------------- Fused gating: scores + grouped top-k, one wave per token ----
__global__ __launch_bounds__(256) void gate_fused_k(const float* __restrict__ x,
                                                    const float* __restrict__ gw,
                                                    const float* __restrict__ gb,
                                                    int* __restrict__ counts,
                                                    int* __restrict__ etok,
                                                    float* __restrict__ ewt)
{
    int t = blockIdx.x * 4 + (threadIdx.x >> 6);
    int lane = threadIdx.x & 63;

    // lane e: dot(x[t], gw[e]) over 512
    const float4* xr = (const float4*)(x + (size_t)t * DIM);
    const float4* wr = (const float4*)(gw + (size_t)lane * DIM);
    float acc = 0.f;
#pragma unroll 8
    for (int i = 0; i < DIM / 4; ++i) {
        float4 xa = xr[i], wa = wr[i];
        acc += xa.x * wa.x + xa.y * wa.y + xa.z * wa.z + xa.w * wa.w;
    }
    float sc = 1.f / (1.f + __expf(-acc));   // pre-bias score
    float s  = sc + gb[lane];                 // biased score

    // group top-2 sum within each 8-lane group (merge (m1,m2) pairs)
    float m1 = s, m2 = -1e30f;
#pragma unroll
    for (int d = 1; d < 8; d <<= 1) {
        float o1 = __shfl_xor(m1, d);
        float o2 = __shfl_xor(m2, d);
        float n1 = fmaxf(m1, o1);
        float n2 = fmaxf(fminf(m1, o1), fmaxf(m2, o2));
        m1 = n1; m2 = n2;
    }
    float gv = m1 + m2;   // uniform within group

    // top-4 groups (tie -> lowest group index)
    bool gkeep = false;
#pragma unroll
    for (int it = 0; it < TOPKG; ++it) {
        float m = gv;
#pragma unroll
        for (int d = 1; d < 64; d <<= 1) m = fmaxf(m, __shfl_xor(m, d));
        unsigned long long mask = __ballot(gv == m);
        int ldr = __ffsll(mask) - 1;
        if ((lane >> 3) == (ldr >> 3)) { gkeep = true; gv = -2e30f; }
    }
    float sv = gkeep ? s : -1e30f;

    // top-8 experts (tie -> lowest index); lane k keeps k-th winner
    float wsum = 0.f;
    int my_e = 0; float my_w = 0.f;
#pragma unroll
    for (int k = 0; k < TOPK; ++k) {
        float m = sv;
#pragma unroll
        for (int d = 1; d < 64; d <<= 1) m = fmaxf(m, __shfl_xor(m, d));
        unsigned long long mask = __ballot(sv == m);
        int l = __ffsll(mask) - 1;
        float wk = __shfl(sc, l);
        wsum += wk;
        if (lane == k) { my_e = l; my_w = wk; }
        if (lane == l) sv = -2e30f;
    }
    float scale = MOE_SCALE / wsum;
    if (lane < TOPK) {
        int p = atomicAdd(&counts[my_e], 1);
        if (p < CAP) {
            etok[my_e * CAP + p] = t;
            ewt[my_e * CAP + p]  = my_w * scale;
        }
    }
}

// ---------------- Weight conversion: fp32 -> bf16 in B-frag-major layout -------
// Frag (16 n x 32 k): element (lane, j) = W[k0 + (lane>>4)*8 + j][n0 + (lane&15)]
// Frag storage: 64 lanes x 8 bf16 contiguous (1 KB). Frag order within expert:
// GEMM1 (w1/w3, k=DIM, n=MOE): idx = nt*16 + kt  (nt<16, kt<16)
// GEMM2 (w2,    k=MOE, n=DIM): idx = nt*8  + kt  (nt<32, kt<8)
__global__ __launch_bounds__(256) void convert_w_k(const float* __restrict__ w1,
                                                   const float* __restrict__ w3,
                                                   const float* __restrict__ w2,
                                                   short* __restrict__ ws1,
                                                   short* __restrict__ ws3,
                                                   short* __restrict__ ws2)
{
    int Wv = blockIdx.x * 4 + (threadIdx.x >> 6);
    int lane = threadIdx.x & 63;
    int q = lane >> 4, m16 = lane & 15;

    const float* src;
    short* dst;
    int ldw;
    if (Wv < 16384) {
        int e = Wv >> 8, rem = Wv & 255, nt = rem >> 4, kt = rem & 15;
        src = w1 + ((size_t)e * DIM + kt * 32 + q * 8) * MOE + nt * 16 + m16;
        dst = ws1 + (size_t)Wv * 512 + lane * 8;
        ldw = MOE;
    } else if (Wv < 32768) {
        int V = Wv - 16384;
        int e = V >> 8, rem = V & 255, nt = rem >> 4, kt = rem & 15;
        src = w3 + ((size_t)e * DIM + kt * 32 + q * 8) * MOE + nt * 16 + m16;
        dst = ws3 + (size_t)V * 512 + lane * 8;
        ldw = MOE;
    } else {
        int V = Wv - 32768;
        int e = V >> 8, rem = V & 255, nt = rem >> 3, kt = rem & 7;
        src = w2 + ((size_t)e * MOE + kt * 32 + q * 8) * DIM + nt * 16 + m16;
        dst = ws2 + (size_t)V * 512 + lane * 8;
        ldw = DIM;
    }
    short o[8];
#pragma unroll
    for (int j = 0; j < 8; ++j) o[j] = (short)f2bf(src[(size_t)j * ldw]);
    *(s16x8*)dst = *(const s16x8*)o;
}

// ---------------- FFN grouped GEMM (B-frags direct from global) ---------------
__global__ __launch_bounds__(256) void ffn_kernel(const float* __restrict__ x,
                                                  const short* __restrict__ ws1,
                                                  const short* __restrict__ ws3,
                                                  const short* __restrict__ ws2,
                                                  const int* __restrict__ counts,
                                                  const int* __restrict__ etok,
                                                  const float* __restrict__ ewt,
                                                  float* __restrict__ out)
{
    __shared__ short Xa[32 * 520];   // 32 tokens x 512 bf16, stride 520
    __shared__ short Ht[32 * 264];   // 32 tokens x 256 bf16, stride 264
    __shared__ int   tok_s[32];
    __shared__ float wt_s[32];

    int e    = blockIdx.x & 63;
    int tile = blockIdx.x >> 6;
    int n_e  = min(counts[e], CAP);
    int r0   = tile * 32;
    if (r0 >= n_e) return;
    int nrows = min(32, n_e - r0);

    int tid = threadIdx.x;
    if (tid < 32) {
        if (tid < nrows) {
            tok_s[tid] = etok[e * CAP + r0 + tid];
            wt_s[tid]  = ewt[e * CAP + r0 + tid];
        } else { tok_s[tid] = 0; wt_s[tid] = 0.f; }
    }
    {
        // 8 threads per token row; each converts 64 fp32 -> 64 bf16
        int r = tid >> 3, c = tid & 7;
        short* dst = Xa + r * 520 + c * 64;
        if (r < nrows) {
            int tok = etok[e * CAP + r0 + r];
            const float4* src = (const float4*)(x + (size_t)tok * DIM + c * 64);
#pragma unroll
            for (int i = 0; i < 16; ++i) {
                float4 f = src[i];
                short4 o;
                o.x = (short)f2bf(f.x); o.y = (short)f2bf(f.y);
                o.z = (short)f2bf(f.z); o.w = (short)f2bf(f.w);
                *(short4*)(dst + i * 4) = o;
            }
        } else {
            short4 z = {0, 0, 0, 0};
#pragma unroll
            for (int i = 0; i < 16; ++i) *(short4*)(dst + i * 4) = z;
        }
    }
    __syncthreads();

    int w = tid >> 6, lane = tid & 63;
    int q = lane >> 4, m16 = lane & 15;
    const int laneoff = lane * 8;

    // ---------------- GEMM1: h1 = X@W1, h3 = X@W3 (wave: 64 n-cols) ----------
    f32x4 acc1[2][4], acc3[2][4];
#pragma unroll
    for (int i = 0; i < 2; ++i)
#pragma unroll
        for (int j = 0; j < 4; ++j) { acc1[i][j] = (f32x4)0.f; acc3[i][j] = (f32x4)0.f; }

    const short* B1 = ws1 + ((size_t)e * 256 + (size_t)w * 4 * 16) * 512 + laneoff;
    const short* B3 = ws3 + ((size_t)e * 256 + (size_t)w * 4 * 16) * 512 + laneoff;
    const short* Arow0 = Xa + m16 * 520 + q * 8;
    const short* Arow1 = Xa + (16 + m16) * 520 + q * 8;

    s16x8 b1a[4], b3a[4], b1b[4], b3b[4], a0a, a1a, a0b, a1b;
#pragma unroll
    for (int nt = 0; nt < 4; ++nt) {
        b1a[nt] = *(const s16x8*)(B1 + (nt * 16) * 512);
        b3a[nt] = *(const s16x8*)(B3 + (nt * 16) * 512);
    }
    a0a = *(const s16x8*)(Arow0);
    a1a = *(const s16x8*)(Arow1);

#pragma unroll
    for (int kt = 0; kt < 16; kt += 2) {
        // prefetch kt+1
#pragma unroll
        for (int nt = 0; nt < 4; ++nt) {
            b1b[nt] = *(const s16x8*)(B1 + (nt * 16 + kt + 1) * 512);
            b3b[nt] = *(const s16x8*)(B3 + (nt * 16 + kt + 1) * 512);
        }
        a0b = *(const s16x8*)(Arow0 + (kt + 1) * 32);
        a1b = *(const s16x8*)(Arow1 + (kt + 1) * 32);
        // compute kt
#pragma unroll
        for (int nt = 0; nt < 4; ++nt) {
            acc1[0][nt] = __builtin_amdgcn_mfma_f32_16x16x32_bf16(a0a, b1a[nt], acc1[0][nt], 0, 0, 0);
            acc1[1][nt] = __builtin_amdgcn_mfma_f32_16x16x32_bf16(a1a, b1a[nt], acc1[1][nt], 0, 0, 0);
            acc3[0][nt] = __builtin_amdgcn_mfma_f32_16x16x32_bf16(a0a, b3a[nt], acc3[0][nt], 0, 0, 0);
            acc3[1][nt] = __builtin_amdgcn_mfma_f32_16x16x32_bf16(a1a, b3a[nt], acc3[1][nt], 0, 0, 0);
        }
        // prefetch kt+2
        if (kt + 2 < 16) {
#pragma unroll
            for (int nt = 0; nt < 4; ++nt) {
                b1a[nt] = *(const s16x8*)(B1 + (nt * 16 + kt + 2) * 512);
                b3a[nt] = *(const s16x8*)(B3 + (nt * 16 + kt + 2) * 512);
            }
            a0a = *(const s16x8*)(Arow0 + (kt + 2) * 32);
            a1a = *(const s16x8*)(Arow1 + (kt + 2) * 32);
        }
        // compute kt+1
#pragma unroll
        for (int nt = 0; nt < 4; ++nt) {
            acc1[0][nt] = __builtin_amdgcn_mfma_f32_16x16x32_bf16(a0b, b1b[nt], acc1[0][nt], 0, 0, 0);
            acc1[1][nt] = __builtin_amdgcn_mfma_f32_16x16x32_bf16(a1b, b1b[nt], acc1[1][nt], 0, 0, 0);
            acc3[0][nt] = __builtin_amdgcn_mfma_f32_16x16x32_bf16(a0b, b3b[nt], acc3[0][nt], 0, 0, 0);
            acc3[1][nt] = __builtin_amdgcn_mfma_f32_16x16x32_bf16(a1b, b3b[nt], acc3[1][nt], 0, 0, 0);
        }
    }

    // SwiGLU -> Ht (bf16); h col m = w*64 + nt*16 + m16, row t = mt*16 + q*4 + r
#pragma unroll
    for (int mt = 0; mt < 2; ++mt)
#pragma unroll
        for (int nt = 0; nt < 4; ++nt)
#pragma unroll
            for (int r = 0; r < 4; ++r) {
                float g = acc1[mt][nt][r];
                float u = acc3[mt][nt][r];
                float hv = g / (1.f + __expf(-g)) * u;
                int t = mt * 16 + q * 4 + r;
                int m = w * 64 + nt * 16 + m16;
                Ht[t * 264 + m] = (short)f2bf(hv);
            }
    __syncthreads();

    // ---------------- GEMM2: Y = H@W2 (wave: 128 n-cols, 8 n-tiles) ----------
    f32x4 acc2[2][8];
#pragma unroll
    for (int i = 0; i < 2; ++i)
#pragma unroll
        for (int j = 0; j < 8; ++j) acc2[i][j] = (f32x4)0.f;

    const short* B2 = ws2 + ((size_t)e * 256 + (size_t)w * 8 * 8) * 512 + laneoff;
    const short* Hrow0 = Ht + m16 * 264 + q * 8;
    const short* Hrow1 = Ht + (16 + m16) * 264 + q * 8;

    s16x8 c2a[8], c2b[8], h0a, h1a, h0b, h1b;
#pragma unroll
    for (int nt = 0; nt < 8; ++nt) c2a[nt] = *(const s16x8*)(B2 + (nt * 8) * 512);
    h0a = *(const s16x8*)(Hrow0);
    h1a = *(const s16x8*)(Hrow1);

#pragma unroll
    for (int kt = 0; kt < 8; kt += 2) {
#pragma unroll
        for (int nt = 0; nt < 8; ++nt)
            c2b[nt] = *(const s16x8*)(B2 + (nt * 8 + kt + 1) * 512);
        h0b = *(const s16x8*)(Hrow0 + (kt + 1) * 32);
        h1b = *(const s16x8*)(Hrow1 + (kt + 1) * 32);
#pragma unroll
        for (int nt = 0; nt < 8; ++nt) {
            acc2[0][nt] = __builtin_amdgcn_mfma_f32_16x16x32_bf16(h0a, c2a[nt], acc2[0][nt], 0, 0, 0);
            acc2[1][nt] = __builtin_amdgcn_mfma_f32_16x16x32_bf16(h1a, c2a[nt], acc2[1][nt], 0, 0, 0);
        }
        if (kt + 2 < 8) {
#pragma unroll
            for (int nt = 0; nt < 8; ++nt)
                c2a[nt] = *(const s16x8*)(B2 + (nt * 8 + kt + 2) * 512);
            h0a = *(const s16x8*)(Hrow0 + (kt + 2) * 32);
            h1a = *(const s16x8*)(Hrow1 + (kt + 2) * 32);
        }
#pragma unroll
        for (int nt = 0; nt < 8; ++nt) {
            acc2[0][nt] = __builtin_amdgcn_mfma_f32_16x16x32_bf16(h0b, c2b[nt], acc2[0][nt], 0, 0, 0);
            acc2[1][nt] = __builtin_amdgcn_mfma_f32_16x16x32_bf16(h1b, c2b[nt], acc2[1][nt], 0, 0, 0);
        }
    }

    // combine: weighted atomic add into out
#pragma unroll
    for (int mt = 0; mt < 2; ++mt)
#pragma unroll
        for (int nt = 0; nt < 8; ++nt)
#pragma unroll
            for (int r = 0; r < 4; ++r) {
                int t = mt * 16 + q * 4 + r;
                if (t < nrows) {
                    int d = (w * 8 + nt) * 16 + m16;
                    float v = acc2[mt][nt][r] * wt_s[t];
                    atomicAdd(out + (size_t)tok_s[t] * DIM + d, v);
                }
            }
}

extern "C" void kernel_launch(void* const* d_in, const int* in_sizes, int n_in,
                              void* d_out, int out_size, void* d_ws, size_t ws_size,
                              hipStream_t stream)
{
    const float* x  = (const float*)d_in[0];
    const float* gw = (const float*)d_in[1];
    const float* gb = (const float*)d_in[2];
    const float* w1 = (const float*)d_in[3];
    const float* w3 = (const float*)d_in[4];
    const float* w2 = (const float*)d_in[5];

    char* ws = (char*)d_ws;
    short* ws1   = (short*)(ws);                     // 16,777,216 B
    short* ws3   = (short*)(ws + 16777216);          // 16,777,216 B
    short* ws2   = (short*)(ws + 33554432);          // 16,777,216 B
    int*   etok  = (int*)  (ws + 50331648);          // 262,144 B
    float* ewt   = (float*)(ws + 50593792);          // 262,144 B
    int*   counts= (int*)  (ws + 50855936);          // 256 B

    hipMemsetAsync(d_out, 0, (size_t)out_size * 4, stream);
    hipMemsetAsync(counts, 0, NE * 4, stream);

    convert_w_k<<<12288, 256, 0, stream>>>(w1, w3, w2, ws1, ws3, ws2);
    gate_fused_k<<<T_TOK / 4, 256, 0, stream>>>(x, gw, gb, counts, etok, ewt);
    ffn_kernel<<<NE * (CAP / 32), 256, 0, stream>>>(x, ws1, ws3, ws2,
                                                    counts, etok, ewt, (float*)d_out);
}